// Round 3
// baseline (19.590 us; speedup 1.0000x reference)
//
#include <hip/hip_runtime.h>
#include <math.h>

#define TPB 256

typedef unsigned short ushort8 __attribute__((ext_vector_type(8)));

// ---------------- ws layout ----------------
// [0, 31360)  : 15680 x ushort (bf16) packed W:  for class c, chunk t (t<196):
//               wp[(c*196+t)*8 + k] = k<4 ? W[c][4t+k] (quantum feats)
//                                   : W[c][784 + cf(4t+k-4)] (classical, permuted to pixel order)
// [31360, 31488): 32 floats: U_u[16], U_v[16]  (folded variational layers per 2-qubit factor)
#define WS_BYTES_NEEDED 31488

__device__ inline float bf2f(unsigned short h) {
    return __uint_as_float(((unsigned int)h) << 16);
}

// =================== prep kernel ===================
__global__ __launch_bounds__(TPB) void quanv_prep_kernel(
    const float* __restrict__ params,  // (L,4)
    const float* __restrict__ W,       // (10,1568)
    unsigned short* __restrict__ wp,   // 15680
    float* __restrict__ Umat,          // 32 floats
    int L)
{
    int e = blockIdx.x * TPB + threadIdx.x;
    if (e < 15680) {
        int c = e / 1568;
        int r = e - c * 1568;
        int t = r >> 3;
        int k = r & 7;
        int src;
        if (k < 4) {
            src = c * 1568 + t * 4 + k;                 // quantum half, identity order
        } else {
            int pix = t * 4 + (k - 4);                  // flat pixel index
            int row = pix / 28, col = pix - row * 28;
            int i = row >> 2, a = row & 3, j = col >> 2, bb = col & 3;
            int cf = ((a * 4 + bb) * 7 + i) * 7 + j;    // classical feature index for this pixel
            src = c * 1568 + 784 + cf;
        }
        float w = W[src];
        unsigned int bits = __float_as_uint(w);
        unsigned int lsb = (bits >> 16) & 1u;           // round-to-nearest-even bf16
        wp[(c * 196 + t) * 8 + k] = (unsigned short)((bits + 0x7FFFu + lsb) >> 16);
    }

    if (blockIdx.x == 0) {
        __shared__ float pc[64], ps[64];
        if (threadIdx.x < 4 * L) {
            float s, c;
            sincosf(params[threadIdx.x] * 0.5f, &s, &c);
            pc[threadIdx.x] = c; ps[threadIdx.x] = s;
        }
        __syncthreads();
        if (threadIdx.x < 2) {
            // fold all layers for factor (wires {0,1} if threadIdx.x==0 else {2,3})
            // state index = wireHi*2 + wireLo ; M maps initial -> final amplitudes
            int off = 2 * threadIdx.x;
            float M[16];
#pragma unroll
            for (int i = 0; i < 16; ++i) M[i] = (i % 5 == 0) ? 1.f : 0.f;
            for (int l = 0; l < L; ++l) {
                float C = pc[4 * l + off], S = ps[4 * l + off];
#pragma unroll
                for (int q = 0; q < 4; ++q) {           // RY on high-bit wire: rows (0,2),(1,3)
                    float a0 = M[0 + q], a2 = M[8 + q];
                    M[0 + q] = C * a0 - S * a2; M[8 + q] = S * a0 + C * a2;
                    float a1 = M[4 + q], a3 = M[12 + q];
                    M[4 + q] = C * a1 - S * a3; M[12 + q] = S * a1 + C * a3;
                }
                C = pc[4 * l + off + 1]; S = ps[4 * l + off + 1];
#pragma unroll
                for (int q = 0; q < 4; ++q) {           // RY on low-bit wire: rows (0,1),(2,3)
                    float a0 = M[0 + q], a1 = M[4 + q];
                    M[0 + q] = C * a0 - S * a1; M[4 + q] = S * a0 + C * a1;
                    float a2 = M[8 + q], a3 = M[12 + q];
                    M[8 + q] = C * a2 - S * a3; M[12 + q] = S * a2 + C * a3;
                }
#pragma unroll
                for (int q = 0; q < 4; ++q) {           // CNOT: where hi==1 flip lo -> swap rows 2,3
                    float tmp = M[8 + q]; M[8 + q] = M[12 + q]; M[12 + q] = tmp;
                }
            }
#pragma unroll
            for (int i = 0; i < 16; ++i) Umat[threadIdx.x * 16 + i] = M[i];
        }
    }
}

// =================== main kernel ===================
__global__ __launch_bounds__(TPB) void quanv_main_kernel(
    const float* __restrict__ x,          // (B,784)
    const unsigned short* __restrict__ wp,
    const float* __restrict__ Umat,
    const float* __restrict__ bias,
    float* __restrict__ out,              // (B,10)
    int B)
{
    __shared__ float img[784];
    __shared__ float Uu[16], Uv[16];
    __shared__ float red[4][10];

    const int b   = blockIdx.x;
    const int tid = threadIdx.x;
    const float* xb = x + (size_t)b * 784;

    if (tid < 196) {
        ((float4*)img)[tid] = ((const float4*)xb)[tid];
    } else if (tid < 196 + 32) {
        int i = tid - 196;
        if (i < 16) Uu[i] = Umat[i]; else Uv[i - 16] = Umat[i + 16 - 16];
        // note: Uv[i-16] = Umat[16 + (i-16)] == Umat[i]
    }
    __syncthreads();

    float acc[10];
#pragma unroll
    for (int c = 0; c < 10; ++c) acc[c] = 0.f;

    if (tid < 196) {
        // ---- patch pixels ----
        int pi = tid / 14, pj = tid - pi * 14;
        float2 top = *(const float2*)&img[2 * pi * 28 + 2 * pj];
        float2 bot = *(const float2*)&img[(2 * pi + 1) * 28 + 2 * pj];
        float x0 = top.x, x1 = top.y, x2 = bot.x, x3 = bot.y;

        float c0 = __cosf(0.5f * x0), s0 = __sinf(0.5f * x0);
        float c1 = __cosf(0.5f * x1), s1 = __sinf(0.5f * x1);
        float c2 = __cosf(0.5f * x2), s2 = __sinf(0.5f * x2);
        float c3 = __cosf(0.5f * x3), s3 = __sinf(0.5f * x3);

        float ui0 = c0 * c1, ui1 = c0 * s1, ui2 = s0 * c1, ui3 = s0 * s1;
        float vi0 = c2 * c3, vi1 = c2 * s3, vi2 = s2 * c3, vi3 = s2 * s3;

        float uf[4], vf[4];
#pragma unroll
        for (int r = 0; r < 4; ++r) {
            uf[r] = fmaf(Uu[r * 4 + 0], ui0, fmaf(Uu[r * 4 + 1], ui1,
                    fmaf(Uu[r * 4 + 2], ui2, Uu[r * 4 + 3] * ui3)));
            vf[r] = fmaf(Uv[r * 4 + 0], vi0, fmaf(Uv[r * 4 + 1], vi1,
                    fmaf(Uv[r * 4 + 2], vi2, Uv[r * 4 + 3] * vi3)));
        }
        float p0 = uf[0] * uf[0], p1 = uf[1] * uf[1], p2 = uf[2] * uf[2], p3 = uf[3] * uf[3];
        float q0 = vf[0] * vf[0], q1 = vf[1] * vf[1], q2 = vf[2] * vf[2], q3 = vf[3] * vf[3];
        float z0 = (p0 + p1) - (p2 + p3);
        float z1 = (p0 + p2) - (p1 + p3);
        float z2 = (q0 + q1) - (q2 + q3);
        float z3 = (q0 + q2) - (q1 + q3);

        // ---- fused dot: quantum (registers) + classical (pixels 4t..4t+3) ----
        float4 cim = ((const float4*)img)[tid];
#pragma unroll
        for (int c = 0; c < 10; ++c) {
            ushort8 w = *(const ushort8*)(wp + (c * 196 + tid) * 8);
            float a;
            a = z0 * bf2f(w[0]);
            a = fmaf(z1, bf2f(w[1]), a);
            a = fmaf(z2, bf2f(w[2]), a);
            a = fmaf(z3, bf2f(w[3]), a);
            a = fmaf(cim.x, bf2f(w[4]), a);
            a = fmaf(cim.y, bf2f(w[5]), a);
            a = fmaf(cim.z, bf2f(w[6]), a);
            a = fmaf(cim.w, bf2f(w[7]), a);
            acc[c] = a;
        }
    }

    // ---- block reduction ----
    const int lane = tid & 63;
    const int wave = tid >> 6;
#pragma unroll
    for (int c = 0; c < 10; ++c) {
        float v = acc[c];
#pragma unroll
        for (int off = 32; off > 0; off >>= 1) v += __shfl_down(v, off, 64);
        if (lane == 0) red[wave][c] = v;
    }
    __syncthreads();

    // ---- bias + log_softmax, parallel over lanes 0..15 ----
    if (tid < 16) {
        float lg = (tid < 10)
                 ? red[0][tid] + red[1][tid] + red[2][tid] + red[3][tid] + bias[tid]
                 : -INFINITY;
        float m = lg;
#pragma unroll
        for (int off = 8; off > 0; off >>= 1) m = fmaxf(m, __shfl_xor(m, off, 16));
        float e = (tid < 10) ? __expf(lg - m) : 0.f;
        float se = e;
#pragma unroll
        for (int off = 8; off > 0; off >>= 1) se += __shfl_xor(se, off, 16);
        if (tid < 10) out[b * 10 + tid] = lg - m - __logf(se);
    }
}

// =================== fallback (round-2 kernel, used if ws too small) ===================
template <int LC>
__global__ __launch_bounds__(TPB) void quanv_fallback_kernel(
    const float* __restrict__ x, const float* __restrict__ params,
    const float* __restrict__ W, const float* __restrict__ bias,
    float* __restrict__ out, int Lrt)
{
    const int L = (LC > 0) ? LC : Lrt;
    __shared__ float img[784];
    __shared__ float feats[1568];
    __shared__ float pco[64], psi[64];
    __shared__ float red[4][10];
    const int b = blockIdx.x, tid = threadIdx.x;
    const float* xb = x + (size_t)b * 784;
    if (tid < 196) ((float4*)img)[tid] = ((const float4*)xb)[tid];
    else { int k = tid - 196; if (k < 4 * L) { float s, c; sincosf(params[k] * 0.5f, &s, &c); pco[k] = c; psi[k] = s; } }
    __syncthreads();
    for (int q = tid; q < 784; q += TPB) {
        int row = q / 28, col = q - row * 28;
        int a = row & 3, i = row >> 2, bb = col & 3, j = col >> 2;
        feats[784 + ((a * 4 + bb) * 7 + i) * 7 + j] = img[q];
    }
    if (tid < 196) {
        int pi = tid / 14, pj = tid - pi * 14;
        const float* r0 = &img[2 * pi * 28 + 2 * pj];
        float x0 = r0[0], x1 = r0[1], x2 = r0[28], x3 = r0[29];
        float c0 = __cosf(0.5f * x0), s0 = __sinf(0.5f * x0);
        float c1 = __cosf(0.5f * x1), s1 = __sinf(0.5f * x1);
        float c2 = __cosf(0.5f * x2), s2 = __sinf(0.5f * x2);
        float c3 = __cosf(0.5f * x3), s3 = __sinf(0.5f * x3);
        float u0 = c0 * c1, u1 = c0 * s1, u2 = s0 * c1, u3 = s0 * s1;
        float v0 = c2 * c3, v1 = c2 * s3, v2 = s2 * c3, v3 = s2 * s3;
#pragma unroll
        for (int l = 0; l < L; ++l) {
            float C, S, t0, t1, t2, t3, tmp;
            C = pco[4 * l]; S = psi[4 * l];
            t0 = C * u0 - S * u2; t2 = S * u0 + C * u2; t1 = C * u1 - S * u3; t3 = S * u1 + C * u3;
            C = pco[4 * l + 1]; S = psi[4 * l + 1];
            u0 = C * t0 - S * t1; u1 = S * t0 + C * t1; u2 = C * t2 - S * t3; u3 = S * t2 + C * t3;
            tmp = u2; u2 = u3; u3 = tmp;
            C = pco[4 * l + 2]; S = psi[4 * l + 2];
            t0 = C * v0 - S * v2; t2 = S * v0 + C * v2; t1 = C * v1 - S * v3; t3 = S * v1 + C * v3;
            C = pco[4 * l + 3]; S = psi[4 * l + 3];
            v0 = C * t0 - S * t1; v1 = S * t0 + C * t1; v2 = C * t2 - S * t3; v3 = S * t2 + C * t3;
            tmp = v2; v2 = v3; v3 = tmp;
        }
        float p0 = u0 * u0, p1 = u1 * u1, p2 = u2 * u2, p3 = u3 * u3;
        float q0 = v0 * v0, q1 = v1 * v1, q2 = v2 * v2, q3 = v3 * v3;
        ((float4*)feats)[tid] = make_float4((p0 + p1) - (p2 + p3), (p0 + p2) - (p1 + p3),
                                            (q0 + q1) - (q2 + q3), (q0 + q2) - (q1 + q3));
    }
    __syncthreads();
    float acc[10];
#pragma unroll
    for (int c = 0; c < 10; ++c) acc[c] = 0.f;
    for (int f = tid; f < 1568; f += TPB) {
        float v = feats[f];
#pragma unroll
        for (int c = 0; c < 10; ++c) acc[c] = fmaf(v, W[c * 1568 + f], acc[c]);
    }
    const int lane = tid & 63, wave = tid >> 6;
#pragma unroll
    for (int c = 0; c < 10; ++c) {
        float v = acc[c];
#pragma unroll
        for (int off = 32; off > 0; off >>= 1) v += __shfl_down(v, off, 64);
        if (lane == 0) red[wave][c] = v;
    }
    __syncthreads();
    if (tid == 0) {
        float lg[10];
#pragma unroll
        for (int c = 0; c < 10; ++c) lg[c] = red[0][c] + red[1][c] + red[2][c] + red[3][c] + bias[c];
        float m = lg[0];
#pragma unroll
        for (int c = 1; c < 10; ++c) m = fmaxf(m, lg[c]);
        float se = 0.f;
#pragma unroll
        for (int c = 0; c < 10; ++c) se += expf(lg[c] - m);
        float lse = logf(se);
#pragma unroll
        for (int c = 0; c < 10; ++c) out[b * 10 + c] = lg[c] - m - lse;
    }
}

extern "C" void kernel_launch(void* const* d_in, const int* in_sizes, int n_in,
                              void* d_out, int out_size, void* d_ws, size_t ws_size,
                              hipStream_t stream) {
    const float* x      = (const float*)d_in[0];
    const float* params = (const float*)d_in[1];
    const float* W      = (const float*)d_in[2];
    const float* bias   = (const float*)d_in[3];
    float* out          = (float*)d_out;

    const int B = in_sizes[0] / 784;
    const int L = in_sizes[1] / 4;

    if (ws_size >= WS_BYTES_NEEDED && L <= 16) {
        unsigned short* wp = (unsigned short*)d_ws;
        float* Umat = (float*)((char*)d_ws + 31360);
        quanv_prep_kernel<<<dim3((15680 + TPB - 1) / TPB), dim3(TPB), 0, stream>>>(params, W, wp, Umat, L);
        quanv_main_kernel<<<dim3(B), dim3(TPB), 0, stream>>>(x, wp, Umat, bias, out, B);
    } else if (L == 4) {
        quanv_fallback_kernel<4><<<dim3(B), dim3(TPB), 0, stream>>>(x, params, W, bias, out, L);
    } else {
        quanv_fallback_kernel<0><<<dim3(B), dim3(TPB), 0, stream>>>(x, params, W, bias, out, L);
    }
}

// Round 6
// 15.491 us; speedup vs baseline: 1.2646x; 1.2646x over previous
//
#include <hip/hip_runtime.h>
#include <math.h>

#define TPB 512   // 8 waves per block, one image per wave; grid = ceil(B/8) -> 1 block/CU at B=2048

typedef unsigned short ushort8 __attribute__((ext_vector_type(8)));
typedef unsigned short ushort4v __attribute__((ext_vector_type(4)));

__device__ inline unsigned short f2bf(float f) {           // round-to-nearest-even
    unsigned int b = __float_as_uint(f);
    unsigned int lsb = (b >> 16) & 1u;
    return (unsigned short)((b + 0x7FFFu + lsb) >> 16);
}
__device__ inline float bf2f(unsigned short h) {
    return __uint_as_float(((unsigned int)h) << 16);
}

// DPP-based wave64 sum (pure VALU, no LDS pipe). ctrl/rmask must be literal constants.
template <int CTRL, int RMASK>
__device__ inline float dpp_add(float v) {
    int t = __builtin_amdgcn_update_dpp(0, __float_as_int(v), CTRL, RMASK, 0xf, false);
    return v + __int_as_float(t);
}
__device__ inline float wave_sum_bcast(float v) {
    v = dpp_add<0x111, 0xf>(v);  // row_shr:1
    v = dpp_add<0x112, 0xf>(v);  // row_shr:2
    v = dpp_add<0x114, 0xf>(v);  // row_shr:4
    v = dpp_add<0x118, 0xf>(v);  // row_shr:8  -> lane15 of each row = row sum
    v = dpp_add<0x142, 0xa>(v);  // row_bcast15 into rows 1,3
    v = dpp_add<0x143, 0xc>(v);  // row_bcast31 into rows 2,3 -> lane 63 = total
    return __int_as_float(__builtin_amdgcn_readlane(__float_as_int(v), 63));
}

__global__ __launch_bounds__(TPB) void quanv_one_kernel(
    const float* __restrict__ x,       // (B,784)
    const float* __restrict__ params,  // (L,4)
    const float* __restrict__ W,       // (10,1568)
    const float* __restrict__ bias,    // (10,)
    float* __restrict__ out,           // (B,10)
    int B, int L)
{
    // bf16 packed weights: wlds[(c*196+t)*8 + k]; k<4: W[c][4t+k] (quantum),
    // k>=4: W[c][784 + g(pixel 4t+k-4)] (classical, permuted to pixel order)
    __shared__ __align__(16) unsigned short wlds[15680];
    __shared__ __align__(16) float umat[32];   // folded U_u[16], U_v[16]

    const int tid  = threadIdx.x;
    const int lane = tid & 63;
    const int wv   = tid >> 6;

    // ---- cooperative W pack: 15680 ushorts = 3920 ushort4 groups ----
    for (int g = tid; g < 3920; g += TPB) {
        int flat = g * 4;                 // ushort index
        int c  = flat / 1568;
        int r  = flat - c * 1568;
        int t  = r >> 3;
        int kh = r & 7;                   // 0 (quantum) or 4 (classical)
        ushort4v o;
        if (kh == 0) {
            float4 q = *(const float4*)(W + c * 1568 + t * 4);
            o[0] = f2bf(q.x); o[1] = f2bf(q.y); o[2] = f2bf(q.z); o[3] = f2bf(q.w);
        } else {
#pragma unroll
            for (int k = 0; k < 4; ++k) {
                int p = t * 4 + k;
                int row = p / 28, col = p - row * 28;
                int gf = (((row & 3) * 4 + (col & 3)) * 7 + (row >> 2)) * 7 + (col >> 2);
                o[k] = f2bf(W[c * 1568 + 784 + gf]);
            }
        }
        *(ushort4v*)(wlds + flat) = o;
    }

    // ---- fold variational layers into 4x4 U per factor (lanes 0,1 of wave 0) ----
    if (tid < 2) {
        const int f = tid;                // 0: wires{0,1}, 1: wires{2,3}
        float M[16];
#pragma unroll
        for (int i = 0; i < 16; ++i) M[i] = (i % 5 == 0) ? 1.f : 0.f;
        for (int l = 0; l < L; ++l) {
            float A = params[4 * l + 2 * f + 0] * 0.5f;
            float C = __cosf(A), S = __sinf(A);
#pragma unroll
            for (int q = 0; q < 4; ++q) {  // RY hi wire: rows (0,2),(1,3)
                float a0 = M[q],     a2 = M[8 + q];
                M[q]      = C * a0 - S * a2;  M[8 + q]  = S * a0 + C * a2;
                float a1 = M[4 + q], a3 = M[12 + q];
                M[4 + q]  = C * a1 - S * a3;  M[12 + q] = S * a1 + C * a3;
            }
            A = params[4 * l + 2 * f + 1] * 0.5f;
            C = __cosf(A); S = __sinf(A);
#pragma unroll
            for (int q = 0; q < 4; ++q) {  // RY lo wire: rows (0,1),(2,3)
                float a0 = M[q],     a1 = M[4 + q];
                M[q]      = C * a0 - S * a1;  M[4 + q]  = S * a0 + C * a1;
                float a2 = M[8 + q], a3 = M[12 + q];
                M[8 + q]  = C * a2 - S * a3;  M[12 + q] = S * a2 + C * a3;
            }
#pragma unroll
            for (int q = 0; q < 4; ++q) {  // CNOT: swap rows 2,3
                float tm = M[8 + q]; M[8 + q] = M[12 + q]; M[12 + q] = tm;
            }
        }
#pragma unroll
        for (int i = 0; i < 16; ++i) umat[f * 16 + i] = M[i];
    }

    __syncthreads();   // the only block barrier

    const int img = blockIdx.x * 8 + wv;
    if (img >= B) return;

    // U into registers (LDS broadcast reads)
    float Um[32];
#pragma unroll
    for (int j = 0; j < 8; ++j) ((float4*)Um)[j] = ((const float4*)umat)[j];

    const float* xb = x + (size_t)img * 784;

    float acc[10];
#pragma unroll
    for (int c = 0; c < 10; ++c) acc[c] = 0.f;

#pragma unroll
    for (int r = 0; r < 4; ++r) {
        int t = r * 64 + lane;
        if (t < 196) {
            int pi = t / 14, pj = t - pi * 14;
            float2 top = *(const float2*)(xb + 56 * pi + 2 * pj);
            float2 bot = *(const float2*)(xb + 56 * pi + 2 * pj + 28);
            float4 cim = *(const float4*)(xb + 4 * t);   // classical pixels for chunk t

            float c0 = __cosf(0.5f * top.x), s0 = __sinf(0.5f * top.x);
            float c1 = __cosf(0.5f * top.y), s1 = __sinf(0.5f * top.y);
            float c2 = __cosf(0.5f * bot.x), s2 = __sinf(0.5f * bot.x);
            float c3 = __cosf(0.5f * bot.y), s3 = __sinf(0.5f * bot.y);

            float ui0 = c0 * c1, ui1 = c0 * s1, ui2 = s0 * c1, ui3 = s0 * s1;
            float vi0 = c2 * c3, vi1 = c2 * s3, vi2 = s2 * c3, vi3 = s2 * s3;

            float uf0 = fmaf(Um[0],  ui0, fmaf(Um[1],  ui1, fmaf(Um[2],  ui2, Um[3]  * ui3)));
            float uf1 = fmaf(Um[4],  ui0, fmaf(Um[5],  ui1, fmaf(Um[6],  ui2, Um[7]  * ui3)));
            float uf2 = fmaf(Um[8],  ui0, fmaf(Um[9],  ui1, fmaf(Um[10], ui2, Um[11] * ui3)));
            float uf3 = fmaf(Um[12], ui0, fmaf(Um[13], ui1, fmaf(Um[14], ui2, Um[15] * ui3)));
            float vf0 = fmaf(Um[16], vi0, fmaf(Um[17], vi1, fmaf(Um[18], vi2, Um[19] * vi3)));
            float vf1 = fmaf(Um[20], vi0, fmaf(Um[21], vi1, fmaf(Um[22], vi2, Um[23] * vi3)));
            float vf2 = fmaf(Um[24], vi0, fmaf(Um[25], vi1, fmaf(Um[26], vi2, Um[27] * vi3)));
            float vf3 = fmaf(Um[28], vi0, fmaf(Um[29], vi1, fmaf(Um[30], vi2, Um[31] * vi3)));

            float p0 = uf0 * uf0, p1 = uf1 * uf1, p2 = uf2 * uf2, p3 = uf3 * uf3;
            float q0 = vf0 * vf0, q1 = vf1 * vf1, q2 = vf2 * vf2, q3 = vf3 * vf3;
            float z0 = (p0 + p1) - (p2 + p3);
            float z1 = (p0 + p2) - (p1 + p3);
            float z2 = (q0 + q1) - (q2 + q3);
            float z3 = (q0 + q2) - (q1 + q3);

#pragma unroll
            for (int c = 0; c < 10; ++c) {
                ushort8 w = *(const ushort8*)(wlds + (c * 196 + t) * 8);
                float a = acc[c];
                a = fmaf(z0,    bf2f(w[0]), a);
                a = fmaf(z1,    bf2f(w[1]), a);
                a = fmaf(z2,    bf2f(w[2]), a);
                a = fmaf(z3,    bf2f(w[3]), a);
                a = fmaf(cim.x, bf2f(w[4]), a);
                a = fmaf(cim.y, bf2f(w[5]), a);
                a = fmaf(cim.z, bf2f(w[6]), a);
                a = fmaf(cim.w, bf2f(w[7]), a);
                acc[c] = a;
            }
        }
    }

    // ---- DPP wave reduction (all-lane uniform results) ----
    float l0 = wave_sum_bcast(acc[0]) + bias[0];
    float l1 = wave_sum_bcast(acc[1]) + bias[1];
    float l2 = wave_sum_bcast(acc[2]) + bias[2];
    float l3 = wave_sum_bcast(acc[3]) + bias[3];
    float l4 = wave_sum_bcast(acc[4]) + bias[4];
    float l5 = wave_sum_bcast(acc[5]) + bias[5];
    float l6 = wave_sum_bcast(acc[6]) + bias[6];
    float l7 = wave_sum_bcast(acc[7]) + bias[7];
    float l8 = wave_sum_bcast(acc[8]) + bias[8];
    float l9 = wave_sum_bcast(acc[9]) + bias[9];

    float m = fmaxf(fmaxf(fmaxf(fmaxf(l0, l1), fmaxf(l2, l3)),
                          fmaxf(fmaxf(l4, l5), fmaxf(l6, l7))),
                    fmaxf(l8, l9));
    float se = __expf(l0 - m) + __expf(l1 - m) + __expf(l2 - m) + __expf(l3 - m) +
               __expf(l4 - m) + __expf(l5 - m) + __expf(l6 - m) + __expf(l7 - m) +
               __expf(l8 - m) + __expf(l9 - m);
    float lse = __logf(se) + m;

    if (lane < 10) {
        float o = l0 - lse;
        o = (lane == 1) ? l1 - lse : o;
        o = (lane == 2) ? l2 - lse : o;
        o = (lane == 3) ? l3 - lse : o;
        o = (lane == 4) ? l4 - lse : o;
        o = (lane == 5) ? l5 - lse : o;
        o = (lane == 6) ? l6 - lse : o;
        o = (lane == 7) ? l7 - lse : o;
        o = (lane == 8) ? l8 - lse : o;
        o = (lane == 9) ? l9 - lse : o;
        out[(size_t)img * 10 + lane] = o;
    }
}

extern "C" void kernel_launch(void* const* d_in, const int* in_sizes, int n_in,
                              void* d_out, int out_size, void* d_ws, size_t ws_size,
                              hipStream_t stream) {
    const float* x      = (const float*)d_in[0];
    const float* params = (const float*)d_in[1];
    const float* W      = (const float*)d_in[2];
    const float* bias   = (const float*)d_in[3];
    float* out          = (float*)d_out;

    const int B = in_sizes[0] / 784;
    const int L = in_sizes[1] / 4;

    const int nblk = (B + 7) / 8;
    quanv_one_kernel<<<dim3(nblk), dim3(TPB), 0, stream>>>(x, params, W, bias, out, B, L);
}

// Round 8
// 14.367 us; speedup vs baseline: 1.3636x; 1.0782x over previous
//
#include <hip/hip_runtime.h>
#include <math.h>

#define TPB 512   // 8 waves per block, one image per wave; grid = ceil(B/8) -> 1 block/CU at B=2048

typedef __fp16 half2v __attribute__((ext_vector_type(2)));
typedef __fp16 half4v __attribute__((ext_vector_type(4)));
typedef __fp16 half8v __attribute__((ext_vector_type(8)));

// DPP-based wave64 sum (pure VALU, no LDS pipe). ctrl/rmask must be literal constants.
template <int CTRL, int RMASK>
__device__ inline float dpp_add(float v) {
    int t = __builtin_amdgcn_update_dpp(0, __float_as_int(v), CTRL, RMASK, 0xf, false);
    return v + __int_as_float(t);
}
__device__ inline float wave_sum_bcast(float v) {
    v = dpp_add<0x111, 0xf>(v);  // row_shr:1
    v = dpp_add<0x112, 0xf>(v);  // row_shr:2
    v = dpp_add<0x114, 0xf>(v);  // row_shr:4
    v = dpp_add<0x118, 0xf>(v);  // row_shr:8  -> lane15 of each row = row sum
    v = dpp_add<0x142, 0xa>(v);  // row_bcast15 into rows 1,3
    v = dpp_add<0x143, 0xc>(v);  // row_bcast31 into rows 2,3 -> lane 63 = total
    return __int_as_float(__builtin_amdgcn_readlane(__float_as_int(v), 63));
}

#if __has_builtin(__builtin_amdgcn_fdot2)
#define HAVE_FDOT2 1
#else
#define HAVE_FDOT2 0
#endif

__global__ __launch_bounds__(TPB) void quanv_one_kernel(
    const float* __restrict__ x,       // (B,784)
    const float* __restrict__ params,  // (L,4)
    const float* __restrict__ W,       // (10,1568)
    const float* __restrict__ bias,    // (10,)
    float* __restrict__ out,           // (B,10)
    int B, int L)
{
    // f16 packed weights: wlds[(c*196+t)*8 + k]; k<4: W[c][4t+k] (quantum),
    // k>=4: W[c][784 + cf(pixel 4t+k-4)] (classical, permuted to pixel order)
    __shared__ __align__(16) __fp16 wlds[15680];
    __shared__ __align__(16) float umat[32];   // folded U_u[16], U_v[16]

    const int tid  = threadIdx.x;
    const int lane = tid & 63;
    const int wv   = tid >> 6;

    // ---- cooperative W pack: 15680 halves = 3920 half4 groups ----
    for (int g = tid; g < 3920; g += TPB) {
        int flat = g * 4;                 // half index
        int c  = flat / 1568;
        int r  = flat - c * 1568;
        int t  = r >> 3;
        int kh = r & 7;                   // 0 (quantum) or 4 (classical)
        half4v o;
        if (kh == 0) {
            float4 q = *(const float4*)(W + c * 1568 + t * 4);
            o[0] = (__fp16)q.x; o[1] = (__fp16)q.y;
            o[2] = (__fp16)q.z; o[3] = (__fp16)q.w;
        } else {
#pragma unroll
            for (int k = 0; k < 4; ++k) {
                int p = t * 4 + k;
                int row = p / 28, col = p - row * 28;
                int gf = (((row & 3) * 4 + (col & 3)) * 7 + (row >> 2)) * 7 + (col >> 2);
                o[k] = (__fp16)W[c * 1568 + 784 + gf];
            }
        }
        *(half4v*)(wlds + flat) = o;
    }

    // ---- fold variational layers into 4x4 U per factor (lanes 0,1 of wave 0) ----
    if (tid < 2) {
        const int f = tid;                // 0: wires{0,1}, 1: wires{2,3}
        float M[16];
#pragma unroll
        for (int i = 0; i < 16; ++i) M[i] = (i % 5 == 0) ? 1.f : 0.f;
        for (int l = 0; l < L; ++l) {
            float A = params[4 * l + 2 * f + 0] * 0.5f;
            float C = __cosf(A), S = __sinf(A);
#pragma unroll
            for (int q = 0; q < 4; ++q) {  // RY hi wire: rows (0,2),(1,3)
                float a0 = M[q],     a2 = M[8 + q];
                M[q]      = C * a0 - S * a2;  M[8 + q]  = S * a0 + C * a2;
                float a1 = M[4 + q], a3 = M[12 + q];
                M[4 + q]  = C * a1 - S * a3;  M[12 + q] = S * a1 + C * a3;
            }
            A = params[4 * l + 2 * f + 1] * 0.5f;
            C = __cosf(A); S = __sinf(A);
#pragma unroll
            for (int q = 0; q < 4; ++q) {  // RY lo wire: rows (0,1),(2,3)
                float a0 = M[q],     a1 = M[4 + q];
                M[q]      = C * a0 - S * a1;  M[4 + q]  = S * a0 + C * a1;
                float a2 = M[8 + q], a3 = M[12 + q];
                M[8 + q]  = C * a2 - S * a3;  M[12 + q] = S * a2 + C * a3;
            }
#pragma unroll
            for (int q = 0; q < 4; ++q) {  // CNOT: swap rows 2,3
                float tm = M[8 + q]; M[8 + q] = M[12 + q]; M[12 + q] = tm;
            }
        }
#pragma unroll
        for (int i = 0; i < 16; ++i) umat[f * 16 + i] = M[i];
    }

    __syncthreads();   // the only block barrier

    const int img = blockIdx.x * 8 + wv;
    if (img >= B) return;

    // U into registers (LDS broadcast reads)
    float Um[32];
#pragma unroll
    for (int j = 0; j < 8; ++j) ((float4*)Um)[j] = ((const float4*)umat)[j];

    const float* xb = x + (size_t)img * 784;

    float acc[10];
#pragma unroll
    for (int c = 0; c < 10; ++c) acc[c] = 0.f;

#pragma unroll
    for (int r = 0; r < 4; ++r) {
        int t = r * 64 + lane;
        if (t < 196) {
            int pi = t / 14, pj = t - pi * 14;
            float2 top = *(const float2*)(xb + 56 * pi + 2 * pj);
            float2 bot = *(const float2*)(xb + 56 * pi + 2 * pj + 28);
            float4 cim = *(const float4*)(xb + 4 * t);   // classical pixels for chunk t

            float c0 = __cosf(0.5f * top.x), s0 = __sinf(0.5f * top.x);
            float c1 = __cosf(0.5f * top.y), s1 = __sinf(0.5f * top.y);
            float c2 = __cosf(0.5f * bot.x), s2 = __sinf(0.5f * bot.x);
            float c3 = __cosf(0.5f * bot.y), s3 = __sinf(0.5f * bot.y);

            float ui0 = c0 * c1, ui1 = c0 * s1, ui2 = s0 * c1, ui3 = s0 * s1;
            float vi0 = c2 * c3, vi1 = c2 * s3, vi2 = s2 * c3, vi3 = s2 * s3;

            float uf0 = fmaf(Um[0],  ui0, fmaf(Um[1],  ui1, fmaf(Um[2],  ui2, Um[3]  * ui3)));
            float uf1 = fmaf(Um[4],  ui0, fmaf(Um[5],  ui1, fmaf(Um[6],  ui2, Um[7]  * ui3)));
            float uf2 = fmaf(Um[8],  ui0, fmaf(Um[9],  ui1, fmaf(Um[10], ui2, Um[11] * ui3)));
            float uf3 = fmaf(Um[12], ui0, fmaf(Um[13], ui1, fmaf(Um[14], ui2, Um[15] * ui3)));
            float vf0 = fmaf(Um[16], vi0, fmaf(Um[17], vi1, fmaf(Um[18], vi2, Um[19] * vi3)));
            float vf1 = fmaf(Um[20], vi0, fmaf(Um[21], vi1, fmaf(Um[22], vi2, Um[23] * vi3)));
            float vf2 = fmaf(Um[24], vi0, fmaf(Um[25], vi1, fmaf(Um[26], vi2, Um[27] * vi3)));
            float vf3 = fmaf(Um[28], vi0, fmaf(Um[29], vi1, fmaf(Um[30], vi2, Um[31] * vi3)));

            float p0 = uf0 * uf0, p1 = uf1 * uf1, p2 = uf2 * uf2, p3 = uf3 * uf3;
            float q0 = vf0 * vf0, q1 = vf1 * vf1, q2 = vf2 * vf2, q3 = vf3 * vf3;
            float z0 = (p0 + p1) - (p2 + p3);
            float z1 = (p0 + p2) - (p1 + p3);
            float z2 = (q0 + q1) - (q2 + q3);
            float z3 = (q0 + q2) - (q1 + q3);

            // pack features to f16 pairs once per chunk (cvt_pkrtz returns v2 __fp16)
            half2v f0 = __builtin_amdgcn_cvt_pkrtz(z0, z1);
            half2v f1 = __builtin_amdgcn_cvt_pkrtz(z2, z3);
            half2v f2 = __builtin_amdgcn_cvt_pkrtz(cim.x, cim.y);
            half2v f3 = __builtin_amdgcn_cvt_pkrtz(cim.z, cim.w);

#pragma unroll
            for (int c = 0; c < 10; ++c) {
                half8v w = *(const half8v*)(wlds + (c * 196 + t) * 8);
                half2v w0 = __builtin_shufflevector(w, w, 0, 1);
                half2v w1 = __builtin_shufflevector(w, w, 2, 3);
                half2v w2 = __builtin_shufflevector(w, w, 4, 5);
                half2v w3 = __builtin_shufflevector(w, w, 6, 7);
                float a = acc[c];
#if HAVE_FDOT2
                a = __builtin_amdgcn_fdot2(f0, w0, a, false);
                a = __builtin_amdgcn_fdot2(f1, w1, a, false);
                a = __builtin_amdgcn_fdot2(f2, w2, a, false);
                a = __builtin_amdgcn_fdot2(f3, w3, a, false);
#else
                a = fmaf((float)f0[0], (float)w0[0], a);
                a = fmaf((float)f0[1], (float)w0[1], a);
                a = fmaf((float)f1[0], (float)w1[0], a);
                a = fmaf((float)f1[1], (float)w1[1], a);
                a = fmaf((float)f2[0], (float)w2[0], a);
                a = fmaf((float)f2[1], (float)w2[1], a);
                a = fmaf((float)f3[0], (float)w3[0], a);
                a = fmaf((float)f3[1], (float)w3[1], a);
#endif
                acc[c] = a;
            }
        }
    }

    // ---- DPP wave reduction (all-lane uniform results) ----
    float l0 = wave_sum_bcast(acc[0]) + bias[0];
    float l1 = wave_sum_bcast(acc[1]) + bias[1];
    float l2 = wave_sum_bcast(acc[2]) + bias[2];
    float l3 = wave_sum_bcast(acc[3]) + bias[3];
    float l4 = wave_sum_bcast(acc[4]) + bias[4];
    float l5 = wave_sum_bcast(acc[5]) + bias[5];
    float l6 = wave_sum_bcast(acc[6]) + bias[6];
    float l7 = wave_sum_bcast(acc[7]) + bias[7];
    float l8 = wave_sum_bcast(acc[8]) + bias[8];
    float l9 = wave_sum_bcast(acc[9]) + bias[9];

    float m = fmaxf(fmaxf(fmaxf(fmaxf(l0, l1), fmaxf(l2, l3)),
                          fmaxf(fmaxf(l4, l5), fmaxf(l6, l7))),
                    fmaxf(l8, l9));
    float se = __expf(l0 - m) + __expf(l1 - m) + __expf(l2 - m) + __expf(l3 - m) +
               __expf(l4 - m) + __expf(l5 - m) + __expf(l6 - m) + __expf(l7 - m) +
               __expf(l8 - m) + __expf(l9 - m);
    float lse = __logf(se) + m;

    if (lane < 10) {
        float o = l0 - lse;
        o = (lane == 1) ? l1 - lse : o;
        o = (lane == 2) ? l2 - lse : o;
        o = (lane == 3) ? l3 - lse : o;
        o = (lane == 4) ? l4 - lse : o;
        o = (lane == 5) ? l5 - lse : o;
        o = (lane == 6) ? l6 - lse : o;
        o = (lane == 7) ? l7 - lse : o;
        o = (lane == 8) ? l8 - lse : o;
        o = (lane == 9) ? l9 - lse : o;
        out[(size_t)img * 10 + lane] = o;
    }
}

extern "C" void kernel_launch(void* const* d_in, const int* in_sizes, int n_in,
                              void* d_out, int out_size, void* d_ws, size_t ws_size,
                              hipStream_t stream) {
    const float* x      = (const float*)d_in[0];
    const float* params = (const float*)d_in[1];
    const float* W      = (const float*)d_in[2];
    const float* bias   = (const float*)d_in[3];
    float* out          = (float*)d_out;

    const int B = in_sizes[0] / 784;
    const int L = in_sizes[1] / 4;

    const int nblk = (B + 7) / 8;
    quanv_one_kernel<<<dim3(nblk), dim3(TPB), 0, stream>>>(x, params, W, bias, out, B, L);
}